// Round 8
// baseline (204.978 us; speedup 1.0000x reference)
//
#include <hip/hip_runtime.h>
#include <hip/hip_bf16.h>

typedef __attribute__((ext_vector_type(4))) float f32x4;
typedef __attribute__((ext_vector_type(8))) short bf16x8;
typedef __attribute__((ext_vector_type(4))) short bf16x4;

#define LDK 264  // shorts per LDS row: K=256 + 8 pad (row stride 528B == 4 mod 32 banks)

__device__ __forceinline__ unsigned cvt2(float lo, float hi) {
    float2 t; t.x = lo; t.y = hi;
    __hip_bfloat162 h = __float22bfloat162_rn(t);   // v_cvt_pk_bf16_f32
    union { __hip_bfloat162 h; unsigned u; } c; c.h = h; return c.u;
}
__device__ __forceinline__ bf16x4 pk4(float a0, float a1, float a2, float a3) {
    union { bf16x4 v; unsigned u[2]; } w;
    w.u[0] = cvt2(a0, a1); w.u[1] = cvt2(a2, a3);
    return w.v;
}

// M=32, K-step=256: each A row is read in ONE 1KB contiguous burst per phase
// (8 back-to-back 128B wave-chunks) -> DRAM page-local. 96 streams/CU instead
// of 256. Single-buffered LDS, raw barriers, loads issued a full phase ahead.
__global__ __launch_bounds__(256, 3) void bmm2_k(const float* __restrict__ a,
                                                 const float* __restrict__ b,
                                                 float* __restrict__ out) {
    // Desc-sorted static ragged tables (M=32: 16*s/32 = s/2 blocks per seq).
    const int  cumblk[9] = {0,1024,1792,2432,2944,3392,3776,4096,4352};
    const int  slen[8]   = {2048,1536,1280,1024,896,768,640,512};
    const long aoff[8]   = {20971520,88080384,135266304,4194304,161480704,125829120,174325760,0};
    const int  toff[8]   = {1536,3584,5888,512,7168,5120,8064,0};

    __shared__ unsigned short As[32 * LDK];   // 16.9 KB
    __shared__ unsigned short Bs[64 * LDK];   // 33.8 KB  (total 49.5 KB -> 3 blocks/CU)

    int bid = blockIdx.x;
    int i = 0;
    #pragma unroll
    for (int t = 0; t < 7; ++t) if (bid >= cumblk[t + 1]) i = t + 1;
    int rem  = bid - cumblk[i];
    int s    = slen[i];
    int nmb  = s >> 5;
    int head = rem / nmb;
    int mb   = rem - head * nmb;

    const float* A  = a + aoff[i] + (long)head * s * s + (long)mb * 32 * s;
    const float* Bp = b + (long)toff[i] * 1024 + head * 64;
    float*       Cp = out + (long)(toff[i] + mb * 32) * 1024 + head * 64;

    int tid = threadIdx.x, lane = tid & 63, wave = tid >> 6;
    int lrow = lane & 15, lgrp = lane >> 4;

    // A staging: thread -> row tid>>3 (0..31), 8 f32x4 at k = (tid&7)*4 + q*32.
    // One wave-instr = 8 rows x 128B; 8 instrs = 1KB sequential per row.
    int arow = tid >> 3, ac = (tid & 7) * 4;
    const float* Arow = A + (long)arow * s;
    // B staging: thread -> 16 tokens (tid>>4)*16.., col-quad (tid&15)*4.
    int bc = (tid & 15) * 4, tb = (tid >> 4) * 16;

    f32x4 rA[8], rB[16];
    f32x4 acc0 = {}, acc1 = {};

    int NP = (s + 255) >> 8;   // phases (896 -> 4, 640 -> 3: last phase is a 128-tail)

    // issue loads for phase with k-base kn; full = (kn+256 <= s)
    auto issue = [&](long kn, bool full) {
        if (full) {
            #pragma unroll
            for (int q = 0; q < 8; ++q)
                rA[q] = __builtin_nontemporal_load((const f32x4*)(Arow + kn + ac + q * 32));
            #pragma unroll
            for (int q = 0; q < 16; ++q)
                rB[q] = *(const f32x4*)(Bp + (kn + tb + q) * 1024 + bc);
        } else {
            #pragma unroll
            for (int q = 0; q < 8; ++q) {
                long k = kn + ac + q * 32;
                long kc = (k < (long)s - 4) ? k : (long)s - 4;   // clamp addr in-bounds
                f32x4 v = __builtin_nontemporal_load((const f32x4*)(Arow + kc));
                if (k >= (long)s) v = (f32x4){0.f, 0.f, 0.f, 0.f}; // zero-fill tail (correctness)
                rA[q] = v;
            }
            #pragma unroll
            for (int q = 0; q < 16; ++q) {
                long tk = kn + tb + q;
                if (tk > (long)s - 1) tk = (long)s - 1;           // clamp (A zeros cover values)
                rB[q] = *(const f32x4*)(Bp + tk * 1024 + bc);
            }
        }
    };

    issue(0, true);   // s >= 512, phase 0 always full

    for (int p = 0; p < NP; ++p) {
        __builtin_amdgcn_s_barrier();   // raw: readers of tile p-1 done (MFMA consumed pre-barrier)

        // stage A (compiler waits vmcnt for rA/rB as needed)
        #pragma unroll
        for (int q = 0; q < 8; ++q)
            *(bf16x4*)&As[arow * LDK + ac + q * 32] = pk4(rA[q][0], rA[q][1], rA[q][2], rA[q][3]);
        // stage B: transpose 4x4 in regs -> Bs[col][k]
        #pragma unroll
        for (int g = 0; g < 4; ++g)
            #pragma unroll
            for (int e = 0; e < 4; ++e)
                *(bf16x4*)&Bs[(bc + e) * LDK + tb + g * 4] =
                    pk4(rB[g*4][e], rB[g*4+1][e], rB[g*4+2][e], rB[g*4+3][e]);

        // issue loads for next phase NOW (full phase of latency cover)
        long kn = (p + 1 < NP) ? ((long)(p + 1) << 8) : 0;
        issue(kn, kn + 256 <= (long)s);

        asm volatile("s_waitcnt lgkmcnt(0)" ::: "memory");
        __builtin_amdgcn_sched_barrier(0);
        __builtin_amdgcn_s_barrier();   // tile p visible

        // compute: 16 MFMA / wave (wave = n-tile; 2 m-tiles)
        #pragma unroll
        for (int ks = 0; ks < 8; ++ks) {
            bf16x8 bf  = *(const bf16x8*)&Bs[(wave * 16 + lrow) * LDK + ks * 32 + lgrp * 8];
            bf16x8 af0 = *(const bf16x8*)&As[lrow * LDK + ks * 32 + lgrp * 8];
            bf16x8 af1 = *(const bf16x8*)&As[(16 + lrow) * LDK + ks * 32 + lgrp * 8];
            acc0 = __builtin_amdgcn_mfma_f32_16x16x32_bf16(af0, bf, acc0, 0, 0, 0);
            acc1 = __builtin_amdgcn_mfma_f32_16x16x32_bf16(af1, bf, acc1, 0, 0, 0);
        }
    }

    // epilogue: C/D layout col=lane&15, row=4*(lane>>4)+reg (verified R1); NT stores
    #pragma unroll
    for (int r = 0; r < 4; ++r) {
        int q0 = lgrp * 4 + r;
        __builtin_nontemporal_store(acc0[r], &Cp[(long)q0 * 1024 + wave * 16 + lrow]);
        __builtin_nontemporal_store(acc1[r], &Cp[(long)(16 + q0) * 1024 + wave * 16 + lrow]);
    }
}

extern "C" void kernel_launch(void* const* d_in, const int* in_sizes, int n_in,
                              void* d_out, int out_size, void* d_ws, size_t ws_size,
                              hipStream_t stream) {
    const float* a = (const float*)d_in[0];
    const float* b = (const float*)d_in[1];
    float* out = (float*)d_out;
    bmm2_k<<<4352, 256, 0, stream>>>(a, b, out);
}